// Round 7
// baseline (386.340 us; speedup 1.0000x reference)
//
#include <hip/hip_runtime.h>
#include <hip/hip_bf16.h>
#include <cstdint>

typedef unsigned short ushort_t;
typedef unsigned int uint_t;
typedef __bf16 bf16x8 __attribute__((ext_vector_type(8)));
typedef float f32x4 __attribute__((ext_vector_type(4)));

#define B_SZ 32
#define C_IN 256
#define C_OUT 256
#define H_SZ 56
#define W_SZ 56
#define HW 3136          // 56*56
#define HP 58            // padded H (halo 1 each side)
#define WP 58            // padded W
#define HPWP 3364
#define BN_EPS 1e-5f
#define K_ZERO 128

__device__ __forceinline__ ushort_t f2bf(float f) {
    unsigned int u = __builtin_bit_cast(unsigned int, f);
    unsigned int r = (u + 0x7fffu + ((u >> 16) & 1u)) >> 16;
    return (ushort_t)r;
}

__device__ __forceinline__ void load_lds16(const void* gptr, void* ldsptr) {
    __builtin_amdgcn_global_load_lds(
        (const __attribute__((address_space(1))) unsigned int*)(uintptr_t)gptr,
        (__attribute__((address_space(3))) unsigned int*)(uintptr_t)ldsptr,
        16, 0, 0);
}

// ---------------------------------------------------------------------------
// Kernel 1 (merged prep): grid (4, 56, 33), block 256.
//  z < 32 : x NCHW fp32 -> padded NHWC bf16 + halo zero + abs-mean partials
//           s_part[b][h][ci] (no atomics, no pre-zero needed).
//  z == 32: weight repack OIHW fp32 -> Wt[tap][co][ci] bf16 (224 blocks loop
//           over 2304 chunks) + BN constants.
// ---------------------------------------------------------------------------
__global__ __launch_bounds__(256) void prep_kernel(const float* __restrict__ x,
                                                   const float* __restrict__ w,
                                                   const float* __restrict__ gamma,
                                                   const float* __restrict__ beta,
                                                   const float* __restrict__ mean,
                                                   const float* __restrict__ var,
                                                   ushort_t* __restrict__ xbp,
                                                   ushort_t* __restrict__ Wt,
                                                   float* __restrict__ bninv,
                                                   float* __restrict__ bnadd,
                                                   float* __restrict__ s_part) {
    const int t = threadIdx.x;
    if (blockIdx.z == 32) {
        const int cid = blockIdx.y * 4 + blockIdx.x;  // 0..223
        for (int chunk = cid; chunk < 2304; chunk += 224) {
            int idx = chunk * 256 + t;
            int tap = idx >> 16;
            int rem = idx & 65535;
            int co = rem >> 8, ci = rem & 255;
            Wt[idx] = f2bf(w[(size_t)(co * C_IN + ci) * 9 + tap]);
        }
        if (cid == 0) {
            float inv = gamma[t] * rsqrtf(var[t] + BN_EPS);
            bninv[t] = inv;
            bnadd[t] = beta[t] - mean[t] * inv;
        }
        return;
    }
    const int cit = blockIdx.x, h = blockIdx.y, b = blockIdx.z;
    __shared__ float tile[64][57];
    __shared__ float red2[256];
    const float* src = x + ((size_t)(b * C_IN + cit * 64) * H_SZ + h) * W_SZ;
    for (int i = t; i < 64 * 14; i += 256) {
        int ci = i / 14, w4 = (i - ci * 14) * 4;
        float4 v = *(const float4*)(src + (size_t)ci * HW + w4);
        tile[ci][w4] = v.x; tile[ci][w4 + 1] = v.y;
        tile[ci][w4 + 2] = v.z; tile[ci][w4 + 3] = v.w;
    }
    __syncthreads();
    {
        int ci = t & 63, wg = t >> 6;
        float a = 0.f;
#pragma unroll
        for (int j = 0; j < 14; j++) a += fabsf(tile[ci][wg * 14 + j]);
        red2[t] = a;
    }
    __syncthreads();
    if (t < 64) {
        float tot = red2[t] + red2[t + 64] + red2[t + 128] + red2[t + 192];
        s_part[((size_t)b * H_SZ + h) * C_IN + cit * 64 + t] = tot * (1.0f / (float)HW);
    }
    const uint2 z2 = make_uint2(0u, 0u);
    for (int i = t; i < W_SZ * 16; i += 256) {
        int w4 = i >> 4, c4 = (i & 15) * 4;
        uint_t lo = (uint_t)f2bf(tile[c4][w4])     | ((uint_t)f2bf(tile[c4 + 1][w4]) << 16);
        uint_t hi = (uint_t)f2bf(tile[c4 + 2][w4]) | ((uint_t)f2bf(tile[c4 + 3][w4]) << 16);
        size_t dst = ((size_t)((b * HP + h + 1) * WP + (w4 + 1))) * C_IN + cit * 64 + c4;
        *(uint2*)&xbp[dst] = make_uint2(lo, hi);
    }
    if (t < 32) {
        int side = t >> 4, c4 = (t & 15) * 4;
        size_t dst = ((size_t)((b * HP + h + 1) * WP + side * 57)) * C_IN + cit * 64 + c4;
        *(uint2*)&xbp[dst] = z2;
    }
    if (h == 0 || h == 55) {
        int prow = (h == 0) ? 0 : 57;
        for (int i = t; i < 58 * 16; i += 256) {
            int w4 = i >> 4, c4 = (i & 15) * 4;
            size_t dst = ((size_t)((b * HP + prow) * WP + w4)) * C_IN + cit * 64 + c4;
            *(uint2*)&xbp[dst] = z2;
        }
    }
}

// ---------------------------------------------------------------------------
// Kernel 2: fused gate + implicit-GEMM conv + BN + ReLU + channel scale.
// Gate prologue: each block reduces s_part for its 1-2 batches, computes
// relu(s@gw^T+gb), zeroes K smallest (tie: lower index), renormalizes ->
// sh_gate in LDS (no tscale global, no gate dispatch).
// Main loop = round-4 structure verbatim (137 us, MfmaUtil 38%, 0 conflicts):
// M128 x N128, BK=64, 16x16x32 MFMA, global_load_lds w=16, XOR swizzle in
// global addr, 3 blocks/CU, XCD-paired grid swizzle.
// ---------------------------------------------------------------------------
__global__ __launch_bounds__(256, 3) void conv_kernel(const ushort_t* __restrict__ xbp,
                                                      const ushort_t* __restrict__ Wt,
                                                      const float* __restrict__ bninv,
                                                      const float* __restrict__ bnadd,
                                                      const float* __restrict__ s_part,
                                                      const float* __restrict__ gw,
                                                      const float* __restrict__ gb,
                                                      float* __restrict__ out) {
    __shared__ __align__(16) ushort_t As[128 * 64];  // 16 KB (gate scratch overlay)
    __shared__ __align__(16) ushort_t Bs[128 * 64];  // 16 KB
    __shared__ float sh_gate[512];                   // tscale for b0 (+ b1)
    const int t = threadIdx.x;
    const int bxr = blockIdx.x;
    const int bx = (bxr >> 4) * 8 + (bxr & 7);   // p tile 0..783
    const int by = (bxr >> 3) & 1;               // co tile 0..1
    const int lane = t & 63;
    const int wv = t >> 6;
    const int waveM = wv >> 1, waveN = wv & 1;

    // ---- gate prologue (tile may straddle two batches: 3136 % 128 != 0)
    const int b0 = (bx * 128) / HW;
    const int b1 = (bx * 128 + 127) / HW;
    {
        float* shs = (float*)As;        // 256 f
        float* shg = (float*)As + 256;  // 256 f
        float* red = (float*)As + 512;  // 256 f
        const int nb = (b1 != b0) ? 2 : 1;
        for (int pb = 0; pb < nb; pb++) {
            const float* sp = s_part + ((size_t)(b0 + pb) * H_SZ) * C_IN + t;
            float sv = 0.f;
            for (int h = 0; h < H_SZ; h++) sv += sp[h * C_IN];
            shs[t] = sv;
            __syncthreads();
            float acc = gb[t];
            const float* wr = gw + (size_t)t * C_IN;
            for (int ci = 0; ci < C_IN; ci++) acc += shs[ci] * wr[ci];
            float g = fmaxf(acc, 0.f);
            shg[t] = g;
            __syncthreads();
            int cnt = 0;
            for (int j = 0; j < C_OUT; j++) {
                float gj = shg[j];
                cnt += (gj < g) || (gj == g && j < t);
            }
            float tv = (cnt >= K_ZERO) ? g : 0.f;
            red[t] = tv;
            __syncthreads();
            for (int off = 128; off > 0; off >>= 1) {
                if (t < off) red[t] += red[t + off];
                __syncthreads();
            }
            sh_gate[pb * 256 + t] = tv * ((float)C_OUT / red[0]);
            __syncthreads();
        }
    }

    // ---- staging addresses (r4): chunk q=i*256+t -> row i*32+(t>>3),
    // stored col t&7, global col (t&7)^(row&7)
    const int srow = t >> 3;
    const int gxor8 = ((t & 7) ^ (srow & 7)) * 8;
    int arow[4], wrow[4];
#pragma unroll
    for (int i = 0; i < 4; i++) {
        int p = bx * 128 + i * 32 + srow;
        int b = p / HW;
        int r = p - b * HW;
        int hh = r / W_SZ, ww = r - hh * W_SZ;
        arow[i] = ((b * HP + hh + 1) * WP + (ww + 1)) * C_IN + gxor8;
        wrow[i] = (by * 128 + i * 32 + srow) * C_IN + gxor8;
    }
    ushort_t* ldsA = As + t * 8;
    ushort_t* ldsB = Bs + t * 8;

    int aoff[2][4], boff[2][4];
#pragma unroll
    for (int ks = 0; ks < 2; ks++) {
        int c = (lane >> 4) + ks * 4;
#pragma unroll
        for (int mt = 0; mt < 4; mt++) {
            int ra = waveM * 64 + mt * 16 + (lane & 15);
            aoff[ks][mt] = (ra * 8 + (c ^ (ra & 7))) * 16;
            int rb = waveN * 64 + mt * 16 + (lane & 15);
            boff[ks][mt] = (rb * 8 + (c ^ (rb & 7))) * 16;
        }
    }

    f32x4 acc[4][4];
#pragma unroll
    for (int i = 0; i < 4; i++)
#pragma unroll
        for (int j = 0; j < 4; j++) acc[i][j] = (f32x4){0.f, 0.f, 0.f, 0.f};

    const char* Ab = (const char*)As;
    const char* Bb = (const char*)Bs;

    for (int tap = 0; tap < 9; tap++) {
        const int doff = ((tap / 3 - 1) * WP + (tap % 3 - 1)) * C_IN;
        const int woff = tap * (C_OUT * C_IN);
#pragma unroll
        for (int cq = 0; cq < 4; cq++) {
            const int ci0 = cq * 64;
#pragma unroll
            for (int i = 0; i < 4; i++) {
                load_lds16(xbp + arow[i] + doff + ci0, ldsA + i * 2048);
                load_lds16(Wt + wrow[i] + woff + ci0, ldsB + i * 2048);
            }
            __syncthreads();
#pragma unroll
            for (int ks = 0; ks < 2; ks++) {
                bf16x8 af[4], bf[4];
#pragma unroll
                for (int mt = 0; mt < 4; mt++) af[mt] = *(const bf16x8*)(Ab + aoff[ks][mt]);
#pragma unroll
                for (int nt = 0; nt < 4; nt++) bf[nt] = *(const bf16x8*)(Bb + boff[ks][nt]);
#pragma unroll
                for (int mt = 0; mt < 4; mt++)
#pragma unroll
                    for (int nt = 0; nt < 4; nt++)
                        acc[mt][nt] = __builtin_amdgcn_mfma_f32_16x16x32_bf16(
                            af[mt], bf[nt], acc[mt][nt], 0, 0, 0);
            }
            __syncthreads();
        }
    }

    // ---- epilogue: y = relu(acc*inv + add) * sh_gate[b][co]
#pragma unroll
    for (int mt = 0; mt < 4; mt++) {
        int p0 = bx * 128 + waveM * 64 + mt * 16 + (lane >> 4) * 4;
        int b = p0 / HW;
        int hw = p0 - b * HW;
        const float* gsel = sh_gate + (b - b0) * 256;
#pragma unroll
        for (int nt = 0; nt < 4; nt++) {
            int co = by * 128 + waveN * 64 + nt * 16 + (lane & 15);
            float inv = bninv[co], add = bnadd[co], tsc = gsel[co];
            float4 o;
            o.x = fmaxf(acc[mt][nt][0] * inv + add, 0.f) * tsc;
            o.y = fmaxf(acc[mt][nt][1] * inv + add, 0.f) * tsc;
            o.z = fmaxf(acc[mt][nt][2] * inv + add, 0.f) * tsc;
            o.w = fmaxf(acc[mt][nt][3] * inv + add, 0.f) * tsc;
            *(float4*)(out + (size_t)(b * C_OUT + co) * HW + hw) = o;
        }
    }
}

// ---------------------------------------------------------------------------
extern "C" void kernel_launch(void* const* d_in, const int* in_sizes, int n_in,
                              void* d_out, int out_size, void* d_ws, size_t ws_size,
                              hipStream_t stream) {
    const float* x      = (const float*)d_in[0];
    const float* conv_w = (const float*)d_in[1];
    const float* gate_w = (const float*)d_in[2];
    const float* gate_b = (const float*)d_in[3];
    const float* bn_g   = (const float*)d_in[4];
    const float* bn_b   = (const float*)d_in[5];
    const float* bn_m   = (const float*)d_in[6];
    const float* bn_v   = (const float*)d_in[7];
    float* out = (float*)d_out;

    char* ws = (char*)d_ws;
    float*    bninv  = (float*)(ws + 0);          // 256 f
    float*    bnadd  = (float*)(ws + 1024);       // 256 f
    float*    s_part = (float*)(ws + 4096);       // 32*56*256 f = 1835008 B
    ushort_t* Wt     = (ushort_t*)(ws + 1839104); // 589824 bf16 = 1179648 B
    ushort_t* xbp    = (ushort_t*)(ws + 3018752); // 32*58*58*256 bf16 = 55115776 B

    prep_kernel<<<dim3(4, 56, 33), 256, 0, stream>>>(x, conv_w, bn_g, bn_b, bn_m, bn_v,
                                                     xbp, Wt, bninv, bnadd, s_part);
    conv_kernel<<<1568, 256, 0, stream>>>(xbp, Wt, bninv, bnadd, s_part,
                                          gate_w, gate_b, out);
}